// Round 3
// baseline (185.624 us; speedup 1.0000x reference)
//
#include <hip/hip_runtime.h>
#include <math.h>

// Problem: [16,1,1024,1024] fp32 pred/target -> scalar weighted mean-abs curvature loss.
// Strategy: 1 block = full 1024-wide row band, 256 threads x 4 cols each (float4),
// rolling 3-row window in separable (hx,hs,rs) basis. Denominators computed
// EXACTLY as the reference (incl. +EPS — it dominates for d1 < 4.6e-6, ~0.1% of
// pixels; dropping it biases the loss by ~8e-3, R2 failure).

constexpr int IMG_B = 16;
constexpr int IMG_H = 1024;
constexpr int IMG_W = 1024;
constexpr int ROWS  = 8;                       // rows per block
constexpr int BLOCK = 256;                     // 256 threads * 4 cols = 1024 = full width
constexpr int TILES_Y = IMG_H / ROWS;          // 128
constexpr int NBLOCKS = IMG_B * TILES_Y;       // 2048
constexpr float EPS = 1e-8f;

// scale constants: p = gx/80, q = gy/80, r = rxx/300, 2s = sxy/200, t = tyy/300
constexpr float A2  = 1.0f / 6400.0f;          // p*q / (gx*gy)
constexpr float Bc  = 1.0f / 300.0f;
constexpr float C2  = 1.0f / 200.0f;           // 2*s / sxy

// per-row separable partials for 4 columns:
// hx = a2-a0 (horiz diff), hs = a0+2a1+a2, rs = a0+a1+a2
struct Row { float hx[4]; float hs[4]; float rs[4]; };

__device__ __forceinline__ void prep_row(const float* __restrict__ A, int y,
                                         bool okl, bool okr, Row& o)
{
    if ((unsigned)y < (unsigned)IMG_H) {       // block-uniform branch
        const size_t off = (size_t)y << 10;
        const float4 v = *reinterpret_cast<const float4*>(A + off);
        const float l = okl ? A[off - 1] : 0.0f;   // left halo (L1-hit)
        const float r = okr ? A[off + 4] : 0.0f;   // right halo (L1-hit)
        const float w[6] = {l, v.x, v.y, v.z, v.w, r};
#pragma unroll
        for (int j = 0; j < 4; ++j) {
            const float e = w[j] + w[j + 2];
            o.hx[j] = w[j + 2] - w[j];
            o.hs[j] = fmaf(2.0f, w[j + 1], e);
            o.rs[j] = e + w[j + 1];
        }
    } else {                                    // zero 'SAME' padding
#pragma unroll
        for (int j = 0; j < 4; ++j) { o.hx[j] = 0.f; o.hs[j] = 0.f; o.rs[j] = 0.f; }
    }
}

// True-scale profile / planform / mean curvature, reference-exact denominators.
__device__ __forceinline__ void curv(const Row& a, const Row& b, const Row& c, int j,
                                     float& prof, float& plan, float& mean)
{
    const float gx  = fmaf(2.0f, b.hx[j], a.hx[j] + c.hx[j]);  // sobel_x (raw)
    const float gy  = c.hs[j] - a.hs[j];                        // sobel_y (raw)
    const float tot = (a.rs[j] + c.rs[j]) + b.rs[j];            // 3x3 sum
    const float H   = (a.hs[j] + c.hs[j]) + b.hs[j];
    const float c1  = H - tot;                                  // middle-column sum
    const float rxx = fmaf(-3.0f, c1, tot);                     // k_xx * 3 (raw)
    const float tyy = fmaf(-3.0f, b.rs[j], tot);                // k_yy * 3 (raw)
    const float sxy = a.hx[j] - c.hx[j];                        // k_xy * 4 (raw)

    const float gx2 = gx * gx, gy2 = gy * gy, gxgy = gx * gy;
    const float g2  = gx2 + gy2;
    const float d1  = A2 * g2;                                  // p^2 + q^2
    const float od  = 1.0f + d1;

    const float sq_od = __builtin_amdgcn_sqrtf(od);
    const float sq_d1 = __builtin_amdgcn_sqrtf(d1);

    // numerators (true scale = A2 * n*)
    const float h1   = fmaf(tyy, gy2, rxx * gx2);
    const float h3   = fmaf(tyy, gx2, rxx * gy2);
    const float h2c  = C2 * (sxy * gxgy);
    const float nprof = A2 * fmaf(Bc, h1, h2c);                 // r*p2+2s*pq+t*q2
    const float nplan = A2 * fmaf(Bc, h3, -h2c);                // r*q2-2s*pq+t*p2
    const float mnum  = fmaf(Bc, rxx + tyy, nplan);             // (1+q2)r-2pq*s+(1+p2)t

    // denominators exactly as reference (EPS included)
    const float den_p = fmaf(d1, sq_od, EPS);                   // d1*sqrt(1+d1)+EPS
    const float den_l = fmaf(d1, sq_d1, EPS);                   // d1^1.5+EPS
    const float den_m = fmaf(od + od, sq_od, EPS);              // 2*(1+d1)^1.5+EPS

    prof = nprof * __builtin_amdgcn_rcpf(den_p);
    plan = nplan * __builtin_amdgcn_rcpf(den_l);
    mean = mnum  * __builtin_amdgcn_rcpf(den_m);
    if (d1 < EPS) { prof = 0.0f; plan = 0.0f; }                 // flat mask
}

__global__ __launch_bounds__(BLOCK) void curv_loss_main(
    const float* __restrict__ pred, const float* __restrict__ targ,
    float* __restrict__ blocksums)
{
    const int tid = threadIdx.x;
    const int b   = blockIdx.x;
    const int img = b >> 7;                 // 128 row-tiles per image
    const int ty  = b & (TILES_Y - 1);
    const int y0  = ty * ROWS;
    const size_t base = (size_t)img * (size_t)(IMG_H * IMG_W) + 4 * tid;
    const float* __restrict__ P = pred + base;
    const float* __restrict__ T = targ + base;
    const bool okl = (tid > 0);
    const bool okr = (tid < BLOCK - 1);

    Row pr[3], tr[3];
    prep_row(P, y0 - 1, okl, okr, pr[0]);
    prep_row(T, y0 - 1, okl, okr, tr[0]);
    prep_row(P, y0,     okl, okr, pr[1]);
    prep_row(T, y0,     okl, okr, tr[1]);

    float acc = 0.0f;
#pragma unroll
    for (int i = 0; i < ROWS; ++i) {
        const int ia = i % 3, ib = (i + 1) % 3, ic = (i + 2) % 3;
        prep_row(P, y0 + i + 1, okl, okr, pr[ic]);
        prep_row(T, y0 + i + 1, okl, okr, tr[ic]);
#pragma unroll
        for (int j = 0; j < 4; ++j) {
            float pp, pl, pm, qp, ql, qm;
            curv(pr[ia], pr[ib], pr[ic], j, pp, pl, pm);
            curv(tr[ia], tr[ib], tr[ic], j, qp, ql, qm);
            acc = fmaf(0.5f, fabsf(pp - qp), acc);
            acc = fmaf(0.3f, fabsf(pl - ql), acc);
            acc = fmaf(0.2f, fabsf(pm - qm), acc);
        }
    }

    // wave64 reduce, then cross-wave via LDS
#pragma unroll
    for (int off = 32; off > 0; off >>= 1) acc += __shfl_down(acc, off, 64);
    __shared__ float ws[BLOCK / 64];
    const int lane = tid & 63, wid = tid >> 6;
    if (lane == 0) ws[wid] = acc;
    __syncthreads();
    if (tid == 0)
        blocksums[b] = (ws[0] + ws[1]) + (ws[2] + ws[3]);
}

__global__ __launch_bounds__(BLOCK) void curv_loss_final(
    const float* __restrict__ blocksums, float* __restrict__ out)
{
    const int tid = threadIdx.x;
    float v = 0.0f;
#pragma unroll
    for (int i = 0; i < NBLOCKS / BLOCK; ++i) v += blocksums[i * BLOCK + tid];
#pragma unroll
    for (int off = 32; off > 0; off >>= 1) v += __shfl_down(v, off, 64);
    __shared__ float ws[BLOCK / 64];
    const int lane = tid & 63, wid = tid >> 6;
    if (lane == 0) ws[wid] = v;
    __syncthreads();
    if (tid == 0) {
        const float tot = (ws[0] + ws[1]) + (ws[2] + ws[3]);
        out[0] = tot * (1.0f / (float)(IMG_B * IMG_H * IMG_W));
    }
}

extern "C" void kernel_launch(void* const* d_in, const int* in_sizes, int n_in,
                              void* d_out, int out_size, void* d_ws, size_t ws_size,
                              hipStream_t stream)
{
    const float* pred = (const float*)d_in[0];
    const float* targ = (const float*)d_in[1];
    float* out = (float*)d_out;
    float* blocksums = (float*)d_ws;   // 2048 floats; every slot written each call

    curv_loss_main<<<NBLOCKS, BLOCK, 0, stream>>>(pred, targ, blocksums);
    curv_loss_final<<<1, BLOCK, 0, stream>>>(blocksums, out);
}